// Round 1
// baseline (634.994 us; speedup 1.0000x reference)
//
#include <hip/hip_runtime.h>
#include <hip/hip_bf16.h>
#include <cstddef>

// Problem constants (match reference)
constexpr int N_NODES = 8192;
constexpr int E_EDGES = 262144;
constexpr int ET = E_EDGES + N_NODES;   // edges + self loops = 270336
constexpr int IN_DIM = 256;
constexpr int HID = 128;
constexpr float NEG_ATT = 0.2f;
constexpr float NEG_ACT = 0.02f;

__device__ inline float lrelu(float v, float s) { return v >= 0.f ? v : s * v; }

__device__ inline void atomicMaxF(float* addr, float v) {
    if (v >= 0.f) atomicMax((int*)addr, __float_as_int(v));
    else          atomicMin((unsigned int*)addr, __float_as_uint(v));
}

// h = x @ W  (one block of 128 threads per node), plus per-node attention
// logits asrc[n] = h[n]·a_src, adst[n] = h[n]·a_dst via block reduction.
__global__ __launch_bounds__(128) void linear_alpha_k(
    const float* __restrict__ x, const float* __restrict__ W,
    const float* __restrict__ a_src, const float* __restrict__ a_dst,
    float* __restrict__ h, float* __restrict__ asrc, float* __restrict__ adst,
    int in_dim)
{
    __shared__ float xs[256];
    __shared__ float red[4];
    const int n = blockIdx.x;
    const int k = threadIdx.x;
    for (int i = k; i < in_dim; i += 128) xs[i] = x[(size_t)n * in_dim + i];
    __syncthreads();
    float acc = 0.f;
    for (int i = 0; i < in_dim; ++i) acc = fmaf(xs[i], W[i * HID + k], acc);
    h[(size_t)n * HID + k] = acc;

    float vs = acc * a_src[k];
    float vd = acc * a_dst[k];
    #pragma unroll
    for (int off = 32; off > 0; off >>= 1) {
        vs += __shfl_down(vs, off, 64);
        vd += __shfl_down(vd, off, 64);
    }
    if ((k & 63) == 0) { red[(k >> 6) * 2 + 0] = vs; red[(k >> 6) * 2 + 1] = vd; }
    __syncthreads();
    if (k == 0) { asrc[n] = red[0] + red[2]; adst[n] = red[1] + red[3]; }
}

// zero accumulator, init m=-inf, denom=0
__global__ void init_layer_k(float* __restrict__ acc, float* __restrict__ m,
                             float* __restrict__ denom)
{
    int i = blockIdx.x * blockDim.x + threadIdx.x;
    if (i < N_NODES * HID) acc[i] = 0.f;
    if (i < N_NODES) { m[i] = -INFINITY; denom[i] = 0.f; }
}

__device__ inline void edge_sd(const int* __restrict__ ei, int i, int& s, int& d)
{
    if (i < E_EDGES) { s = ei[i]; d = ei[E_EDGES + i]; }
    else             { s = i - E_EDGES; d = s; }
}

__global__ void edge_max_k(const int* __restrict__ ei,
                           const float* __restrict__ asrc, const float* __restrict__ adst,
                           float* __restrict__ m)
{
    int i = blockIdx.x * blockDim.x + threadIdx.x;
    if (i >= ET) return;
    int s, d; edge_sd(ei, i, s, d);
    float v = lrelu(asrc[s] + adst[d], NEG_ATT);
    atomicMaxF(&m[d], v);
}

__global__ void edge_sum_k(const int* __restrict__ ei,
                           const float* __restrict__ asrc, const float* __restrict__ adst,
                           const float* __restrict__ m, float* __restrict__ denom)
{
    int i = blockIdx.x * blockDim.x + threadIdx.x;
    if (i >= ET) return;
    int s, d; edge_sd(ei, i, s, d);
    float v = lrelu(asrc[s] + adst[d], NEG_ATT);
    atomicAdd(&denom[d], expf(v - m[d]));
}

// one block (128 threads) per edge: acc[d] += alpha * h[s]
__global__ __launch_bounds__(128) void aggregate_k(
    const int* __restrict__ ei,
    const float* __restrict__ asrc, const float* __restrict__ adst,
    const float* __restrict__ m, const float* __restrict__ denom,
    const float* __restrict__ h, float* __restrict__ acc)
{
    int i = blockIdx.x;
    int s, d; edge_sd(ei, i, s, d);
    float v = lrelu(asrc[s] + adst[d], NEG_ATT);
    float alpha = expf(v - m[d]) / denom[d];
    int k = threadIdx.x;
    atomicAdd(&acc[(size_t)d * HID + k], alpha * h[(size_t)s * HID + k]);
}

__global__ void bias_act_k(const float* __restrict__ acc_in,
                           const float* __restrict__ b, float* __restrict__ out)
{
    int i = blockIdx.x * blockDim.x + threadIdx.x;
    if (i >= N_NODES * HID) return;
    float v = acc_in[i] + b[i & (HID - 1)];
    out[i] = lrelu(v, NEG_ACT);
}

// C = A * A^T, A: [8192][128] fp32, C: [8192][8192].
// 64x64 tile per 256-thread block, 4x4 micro-tile per thread,
// XOR quad-swizzled LDS (float4 col c4 stored at c4 ^ ((row>>2)&7)).
__global__ __launch_bounds__(256) void aat_k(const float* __restrict__ A,
                                             float* __restrict__ C)
{
    __shared__ float As[64 * 128];
    __shared__ float Bs[64 * 128];
    const int t = threadIdx.x;
    const int bi = blockIdx.y * 64;
    const int bj = blockIdx.x * 64;

    for (int idx = t; idx < 64 * 32; idx += 256) {
        int r = idx >> 5, c4 = idx & 31;
        int sc4 = c4 ^ ((r >> 2) & 7);
        float4 va = ((const float4*)(A + (size_t)(bi + r) * HID))[c4];
        float4 vb = ((const float4*)(A + (size_t)(bj + r) * HID))[c4];
        ((float4*)As)[r * 32 + sc4] = va;
        ((float4*)Bs)[r * 32 + sc4] = vb;
    }
    __syncthreads();

    const int tx = t & 15, ty = t >> 4;
    float acc[4][4] = {};
    #pragma unroll 4
    for (int k4 = 0; k4 < 32; ++k4) {
        float4 a[4], b[4];
        #pragma unroll
        for (int r = 0; r < 4; ++r) {
            int row = ty * 4 + r;
            a[r] = ((const float4*)As)[row * 32 + (k4 ^ ((row >> 2) & 7))];
        }
        #pragma unroll
        for (int c = 0; c < 4; ++c) {
            int row = tx * 4 + c;
            b[c] = ((const float4*)Bs)[row * 32 + (k4 ^ ((row >> 2) & 7))];
        }
        #pragma unroll
        for (int r = 0; r < 4; ++r)
            #pragma unroll
            for (int c = 0; c < 4; ++c) {
                acc[r][c] = fmaf(a[r].x, b[c].x, acc[r][c]);
                acc[r][c] = fmaf(a[r].y, b[c].y, acc[r][c]);
                acc[r][c] = fmaf(a[r].z, b[c].z, acc[r][c]);
                acc[r][c] = fmaf(a[r].w, b[c].w, acc[r][c]);
            }
    }

    #pragma unroll
    for (int r = 0; r < 4; ++r) {
        int row = bi + ty * 4 + r;
        float4 v = make_float4(acc[r][0], acc[r][1], acc[r][2], acc[r][3]);
        *(float4*)(C + (size_t)row * N_NODES + bj + tx * 4) = v;
    }
}

extern "C" void kernel_launch(void* const* d_in, const int* in_sizes, int n_in,
                              void* d_out, int out_size, void* d_ws, size_t ws_size,
                              hipStream_t stream)
{
    const float* x    = (const float*)d_in[0];
    const int*   ei   = (const int*)d_in[1];   // [2][E] int32 (jax x64 off)
    const float* W1   = (const float*)d_in[2];
    const float* a1s  = (const float*)d_in[3];
    const float* a1d  = (const float*)d_in[4];
    const float* b1   = (const float*)d_in[5];
    const float* W2   = (const float*)d_in[6];
    const float* a2s  = (const float*)d_in[7];
    const float* a2d  = (const float*)d_in[8];
    const float* b2   = (const float*)d_in[9];
    float* C = (float*)d_out;

    float* ws   = (float*)d_ws;
    float* h    = ws;                     // N*HID
    float* acc  = ws + 1048576;           // N*HID
    float* act1 = ws + 2097152;           // N*HID
    float* asrc = ws + 3145728;           // N
    float* adst = asrc + N_NODES;         // N
    float* m    = adst + N_NODES;         // N
    float* den  = m + N_NODES;            // N

    const int edge_blocks = (ET + 255) / 256;
    const int nh_blocks = (N_NODES * HID + 255) / 256;

    // ---- layer 1 ----
    linear_alpha_k<<<N_NODES, 128, 0, stream>>>(x, W1, a1s, a1d, h, asrc, adst, IN_DIM);
    init_layer_k<<<nh_blocks, 256, 0, stream>>>(acc, m, den);
    edge_max_k<<<edge_blocks, 256, 0, stream>>>(ei, asrc, adst, m);
    edge_sum_k<<<edge_blocks, 256, 0, stream>>>(ei, asrc, adst, m, den);
    aggregate_k<<<ET, 128, 0, stream>>>(ei, asrc, adst, m, den, h, acc);
    bias_act_k<<<nh_blocks, 256, 0, stream>>>(acc, b1, act1);

    // ---- layer 2 ----
    linear_alpha_k<<<N_NODES, 128, 0, stream>>>(act1, W2, a2s, a2d, h, asrc, adst, HID);
    init_layer_k<<<nh_blocks, 256, 0, stream>>>(acc, m, den);
    edge_max_k<<<edge_blocks, 256, 0, stream>>>(ei, asrc, adst, m);
    edge_sum_k<<<edge_blocks, 256, 0, stream>>>(ei, asrc, adst, m, den);
    aggregate_k<<<ET, 128, 0, stream>>>(ei, asrc, adst, m, den, h, acc);
    bias_act_k<<<nh_blocks, 256, 0, stream>>>(acc, b2, acc);  // act2 in place

    // ---- pred = act2 @ act2^T ----
    dim3 ggrid(N_NODES / 64, N_NODES / 64);
    aat_k<<<ggrid, 256, 0, stream>>>(acc, C);
}

// Round 2
// 269.026 us; speedup vs baseline: 2.3603x; 2.3603x over previous
//
#include <hip/hip_runtime.h>
#include <cstddef>
#include <cstdint>

constexpr int N_NODES = 8192;
constexpr int E_EDGES = 262144;
constexpr int ET = E_EDGES + N_NODES;   // + self loops
constexpr int IN_DIM = 256;
constexpr int HID = 128;
constexpr float NEG_ATT = 0.2f;
constexpr float NEG_ACT = 0.02f;

typedef __attribute__((ext_vector_type(8))) short bf16x8;
typedef __attribute__((ext_vector_type(4))) float f32x4;

__device__ inline float lrelu(float v, float s) { return v >= 0.f ? v : s * v; }

// ---------------- graph build (CSR by destination) ----------------
__global__ void hist_k(const int* __restrict__ ei, int* __restrict__ cnt) {
    int i = blockIdx.x * blockDim.x + threadIdx.x;
    if (i >= ET) return;
    int d = (i < E_EDGES) ? ei[E_EDGES + i] : (i - E_EDGES);
    atomicAdd(&cnt[d], 1);
}

__global__ __launch_bounds__(1024) void scan_k(const int* __restrict__ cnt,
                                               int* __restrict__ rowptr) {
    __shared__ int part[1024];
    const int t = threadIdx.x;
    int loc[8]; int s = 0;
    #pragma unroll
    for (int j = 0; j < 8; ++j) { loc[j] = s; s += cnt[t * 8 + j]; }
    part[t] = s;
    __syncthreads();
    for (int off = 1; off < 1024; off <<= 1) {
        int v = (t >= off) ? part[t - off] : 0;
        __syncthreads();
        part[t] += v;
        __syncthreads();
    }
    int pre = (t == 0) ? 0 : part[t - 1];
    #pragma unroll
    for (int j = 0; j < 8; ++j) rowptr[t * 8 + j] = pre + loc[j];
    if (t == 1023) rowptr[8192] = part[1023];
}

__global__ void scatter_k(const int* __restrict__ ei, const int* __restrict__ rowptr,
                          int* __restrict__ cnt, int* __restrict__ csr) {
    int i = blockIdx.x * blockDim.x + threadIdx.x;
    if (i >= ET) return;
    int s, d;
    if (i < E_EDGES) { s = ei[i]; d = ei[E_EDGES + i]; }
    else             { s = i - E_EDGES; d = s; }
    int pos = rowptr[d] + atomicAdd(&cnt[d], 1);
    csr[pos] = s;
}

// ---------------- h = x@W + attention logits (8 nodes / block) ----------------
__global__ __launch_bounds__(128) void linear_alpha_k(
    const float* __restrict__ x, const float* __restrict__ W,
    const float* __restrict__ a_src, const float* __restrict__ a_dst,
    float* __restrict__ h, float* __restrict__ asrc, float* __restrict__ adst,
    int in_dim)
{
    __shared__ float xs[8][256];
    __shared__ float red[2][8][2];
    const int t = threadIdx.x;
    const int n0 = blockIdx.x * 8;
    for (int n = 0; n < 8; ++n)
        for (int i = t; i < in_dim; i += 128) xs[n][i] = x[(size_t)(n0 + n) * in_dim + i];
    __syncthreads();
    float acc[8] = {0.f,0.f,0.f,0.f,0.f,0.f,0.f,0.f};
    for (int i = 0; i < in_dim; ++i) {
        float wv = W[i * HID + t];
        #pragma unroll
        for (int n = 0; n < 8; ++n) acc[n] = fmaf(xs[n][i], wv, acc[n]);
    }
    #pragma unroll
    for (int n = 0; n < 8; ++n) h[(size_t)(n0 + n) * HID + t] = acc[n];
    const float As = a_src[t], Ad = a_dst[t];
    const int wv_ = t >> 6;
    #pragma unroll
    for (int n = 0; n < 8; ++n) {
        float vs = acc[n] * As, vd = acc[n] * Ad;
        #pragma unroll
        for (int off = 32; off; off >>= 1) {
            vs += __shfl_down(vs, off, 64);
            vd += __shfl_down(vd, off, 64);
        }
        if ((t & 63) == 0) { red[wv_][n][0] = vs; red[wv_][n][1] = vd; }
    }
    __syncthreads();
    if (t < 8) {
        asrc[n0 + t] = red[0][t][0] + red[1][t][0];
        adst[n0 + t] = red[0][t][1] + red[1][t][1];
    }
}

// -------- fused segment softmax + aggregate + bias + leakyrelu (block per dst) --------
__global__ __launch_bounds__(128) void gat_agg_k(
    const int* __restrict__ rowptr, const int* __restrict__ csr,
    const float* __restrict__ asrc, const float* __restrict__ adst,
    const float* __restrict__ h, const float* __restrict__ bias,
    float* __restrict__ out)
{
    __shared__ float w[2048];
    __shared__ int   si[2048];
    __shared__ float redm[2], reds[2];
    const int d = blockIdx.x;
    const int beg = rowptr[d];
    const int deg = rowptr[d + 1] - beg;
    const int t = threadIdx.x;
    const float ad = adst[d];

    float mx = -INFINITY;
    for (int j = t; j < deg; j += 128) {
        int s = csr[beg + j];
        float e = asrc[s] + ad; e = e >= 0.f ? e : NEG_ATT * e;
        if (j < 2048) { w[j] = e; si[j] = s; }
        mx = fmaxf(mx, e);
    }
    #pragma unroll
    for (int off = 32; off; off >>= 1) mx = fmaxf(mx, __shfl_down(mx, off, 64));
    if ((t & 63) == 0) redm[t >> 6] = mx;
    __syncthreads();
    const float M = fmaxf(redm[0], redm[1]);

    float sm = 0.f;
    for (int j = t; j < deg; j += 128) {
        float e;
        if (j < 2048) e = w[j];
        else { int s = csr[beg + j]; e = asrc[s] + ad; e = e >= 0.f ? e : NEG_ATT * e; }
        float ww = __expf(e - M);
        if (j < 2048) w[j] = ww;
        sm += ww;
    }
    #pragma unroll
    for (int off = 32; off; off >>= 1) sm += __shfl_down(sm, off, 64);
    if ((t & 63) == 0) reds[t >> 6] = sm;
    __syncthreads();
    const float inv = 1.f / (reds[0] + reds[1]);

    float acc = 0.f;
    for (int j = 0; j < deg; ++j) {
        int s; float ww;
        if (j < 2048) { s = si[j]; ww = w[j]; }
        else {
            s = csr[beg + j];
            float e = asrc[s] + ad; e = e >= 0.f ? e : NEG_ATT * e;
            ww = __expf(e - M);
        }
        acc = fmaf(ww, h[(size_t)s * HID + t], acc);
    }
    out[(size_t)d * HID + t] = lrelu(fmaf(acc, inv, bias[t]), NEG_ACT);
}

// ---------------- fp32 -> bf16 (hi, lo) split ----------------
__global__ void cvt_k(const float* __restrict__ a,
                      unsigned short* __restrict__ hi, unsigned short* __restrict__ lo) {
    int i = blockIdx.x * blockDim.x + threadIdx.x;
    float v = a[i];
    uint32_t u = __float_as_uint(v);
    uint32_t rh = (u + 0x7FFFu + ((u >> 16) & 1u)) & 0xFFFF0000u;   // RNE to bf16
    float hf = __uint_as_float(rh);
    float r = v - hf;
    uint32_t u2 = __float_as_uint(r);
    uint32_t rl = (u2 + 0x7FFFu + ((u2 >> 16) & 1u)) & 0xFFFF0000u;
    hi[i] = (unsigned short)(rh >> 16);
    lo[i] = (unsigned short)(rl >> 16);
}

// ---------------- C = A A^T via split-bf16 MFMA ----------------
// 128x128 tile / block (256 thr = 4 waves, each a 64x64 subtile of 4x4 16x16 frags).
// LDS: 4 panels [128 rows][64 k] bf16, 16B-chunk XOR swizzle (slot = c ^ (r&7)).
__global__ __launch_bounds__(256) void aat_mfma_k(
    const unsigned short* __restrict__ hi, const unsigned short* __restrict__ lo,
    float* __restrict__ C)
{
    __shared__ __align__(16) unsigned short sm[4][128 * 64];
    const int t = threadIdx.x;
    const int lane = t & 63, wv = t >> 6;
    const int bi = blockIdx.y * 128, bj = blockIdx.x * 128;
    const int wi0 = (wv >> 1) * 64, wj0 = (wv & 1) * 64;
    const int lr = lane & 15, g = lane >> 4;

    f32x4 acc[4][4] = {};

    const unsigned short* gsrc[4] = { hi, lo, hi, lo };
    const int gbase[4] = { bi, bi, bj, bj };

    for (int ks = 0; ks < 2; ++ks) {
        if (ks) __syncthreads();           // finish compute before re-staging
        #pragma unroll
        for (int arr = 0; arr < 4; ++arr) {
            const unsigned short* src = gsrc[arr];
            const int rb = gbase[arr];
            #pragma unroll
            for (int it = 0; it < 4; ++it) {
                int idx = it * 256 + t;
                int r = idx >> 3, c = idx & 7;
                float4 v = *(const float4*)(src + (size_t)(rb + r) * HID + ks * 64 + c * 8);
                ((float4*)sm[arr])[r * 8 + (c ^ (r & 7))] = v;
            }
        }
        __syncthreads();

        #pragma unroll
        for (int kw = 0; kw < 2; ++kw) {
            bf16x8 ah[4], al[4], bh[4], bl[4];
            #pragma unroll
            for (int f = 0; f < 4; ++f) {
                int rA = wi0 + f * 16 + lr;
                int csA = (kw * 4 + g) ^ (rA & 7);
                ah[f] = *(const bf16x8*)(sm[0] + rA * 64 + csA * 8);
                al[f] = *(const bf16x8*)(sm[1] + rA * 64 + csA * 8);
                int rB = wj0 + f * 16 + lr;
                int csB = (kw * 4 + g) ^ (rB & 7);
                bh[f] = *(const bf16x8*)(sm[2] + rB * 64 + csB * 8);
                bl[f] = *(const bf16x8*)(sm[3] + rB * 64 + csB * 8);
            }
            #pragma unroll
            for (int fi = 0; fi < 4; ++fi)
                #pragma unroll
                for (int fj = 0; fj < 4; ++fj) {
                    acc[fi][fj] = __builtin_amdgcn_mfma_f32_16x16x32_bf16(ah[fi], bh[fj], acc[fi][fj], 0, 0, 0);
                    acc[fi][fj] = __builtin_amdgcn_mfma_f32_16x16x32_bf16(ah[fi], bl[fj], acc[fi][fj], 0, 0, 0);
                    acc[fi][fj] = __builtin_amdgcn_mfma_f32_16x16x32_bf16(al[fi], bh[fj], acc[fi][fj], 0, 0, 0);
                    acc[fi][fj] = __builtin_amdgcn_mfma_f32_16x16x32_bf16(al[fi], bl[fj], acc[fi][fj], 0, 0, 0);
                }
        }
    }

    #pragma unroll
    for (int fi = 0; fi < 4; ++fi)
        #pragma unroll
        for (int q = 0; q < 4; ++q) {
            size_t row = (size_t)(bi + wi0 + fi * 16 + g * 4 + q);
            float* cp = C + row * N_NODES + bj + wj0 + lr;
            #pragma unroll
            for (int fj = 0; fj < 4; ++fj)
                __builtin_nontemporal_store(acc[fi][fj][q], cp + fj * 16);
        }
}

extern "C" void kernel_launch(void* const* d_in, const int* in_sizes, int n_in,
                              void* d_out, int out_size, void* d_ws, size_t ws_size,
                              hipStream_t stream)
{
    const float* x   = (const float*)d_in[0];
    const int*   ei  = (const int*)d_in[1];
    const float* W1  = (const float*)d_in[2];
    const float* a1s = (const float*)d_in[3];
    const float* a1d = (const float*)d_in[4];
    const float* b1  = (const float*)d_in[5];
    const float* W2  = (const float*)d_in[6];
    const float* a2s = (const float*)d_in[7];
    const float* a2d = (const float*)d_in[8];
    const float* b2  = (const float*)d_in[9];
    float* C = (float*)d_out;

    // workspace layout (12 MB total)
    char* base = (char*)d_ws;
    float* h   = (float*)base;                       // 4 MB
    float* act = (float*)(base + (4u << 20));        // 4 MB (act1, then act2)
    char*  aux = base + (8u << 20);                  // 4 MB multi-use
    float* asrc   = (float*)aux;                     // 32 KB
    float* adst   = (float*)(aux + (32u << 10));     // 32 KB
    int*   rowptr = (int*)(aux + (64u << 10));       // 8193 ints
    int*   cnt    = (int*)(aux + (100u << 10));      // 32 KB
    int*   csr    = (int*)(aux + (132u << 10));      // ~1.03 MB
    // after layer 2, graph data dead -> reuse aux for bf16 panels
    unsigned short* hi = (unsigned short*)aux;               // 2 MB
    unsigned short* lo = (unsigned short*)(aux + (2u << 20)); // 2 MB

    const int eb = (ET + 255) / 256;

    // CSR build (shared by both layers)
    hipMemsetAsync(cnt, 0, N_NODES * sizeof(int), stream);
    hist_k<<<eb, 256, 0, stream>>>(ei, cnt);
    scan_k<<<1, 1024, 0, stream>>>(cnt, rowptr);
    hipMemsetAsync(cnt, 0, N_NODES * sizeof(int), stream);
    scatter_k<<<eb, 256, 0, stream>>>(ei, rowptr, cnt, csr);

    // layer 1
    linear_alpha_k<<<N_NODES / 8, 128, 0, stream>>>(x, W1, a1s, a1d, h, asrc, adst, IN_DIM);
    gat_agg_k<<<N_NODES, 128, 0, stream>>>(rowptr, csr, asrc, adst, h, b1, act);
    // layer 2
    linear_alpha_k<<<N_NODES / 8, 128, 0, stream>>>(act, W2, a2s, a2d, h, asrc, adst, HID);
    gat_agg_k<<<N_NODES, 128, 0, stream>>>(rowptr, csr, asrc, adst, h, b2, act);

    // pred = act @ act^T via split bf16
    cvt_k<<<(N_NODES * HID) / 256, 256, 0, stream>>>(act, hi, lo);
    aat_mfma_k<<<dim3(N_NODES / 128, N_NODES / 128), 256, 0, stream>>>(hi, lo, C);
}

// Round 3
// 246.160 us; speedup vs baseline: 2.5796x; 1.0929x over previous
//
#include <hip/hip_runtime.h>
#include <cstddef>
#include <cstdint>

constexpr int N_NODES = 8192;
constexpr int E_EDGES = 262144;
constexpr int ET = E_EDGES + N_NODES;   // + self loops
constexpr int IN_DIM = 256;
constexpr int HID = 128;
constexpr float NEG_ATT = 0.2f;
constexpr float NEG_ACT = 0.02f;

typedef __attribute__((ext_vector_type(8))) short bf16x8;
typedef __attribute__((ext_vector_type(4))) float f32x4;

__device__ inline float lrelu(float v, float s) { return v >= 0.f ? v : s * v; }

// ---------------- graph build (CSR by destination) ----------------
__global__ __launch_bounds__(1024) void zero_k(int* __restrict__ cnt) {
    cnt[blockIdx.x * 1024 + threadIdx.x] = 0;
}

__global__ void hist_k(const int* __restrict__ ei, int* __restrict__ cnt) {
    int i = blockIdx.x * blockDim.x + threadIdx.x;
    if (i >= ET) return;
    int d = (i < E_EDGES) ? ei[E_EDGES + i] : (i - E_EDGES);
    atomicAdd(&cnt[d], 1);
}

// exclusive scan of cnt -> rowptr; also re-zeroes cnt for scatter_k
__global__ __launch_bounds__(1024) void scan_k(int* __restrict__ cnt,
                                               int* __restrict__ rowptr) {
    __shared__ int part[1024];
    const int t = threadIdx.x;
    int loc[8]; int s = 0;
    #pragma unroll
    for (int j = 0; j < 8; ++j) { loc[j] = s; s += cnt[t * 8 + j]; }
    part[t] = s;
    __syncthreads();
    for (int off = 1; off < 1024; off <<= 1) {
        int v = (t >= off) ? part[t - off] : 0;
        __syncthreads();
        part[t] += v;
        __syncthreads();
    }
    int pre = (t == 0) ? 0 : part[t - 1];
    #pragma unroll
    for (int j = 0; j < 8; ++j) { rowptr[t * 8 + j] = pre + loc[j]; cnt[t * 8 + j] = 0; }
    if (t == 1023) rowptr[8192] = part[1023];
}

__global__ void scatter_k(const int* __restrict__ ei, const int* __restrict__ rowptr,
                          int* __restrict__ cnt, int* __restrict__ csr) {
    int i = blockIdx.x * blockDim.x + threadIdx.x;
    if (i >= ET) return;
    int s, d;
    if (i < E_EDGES) { s = ei[i]; d = ei[E_EDGES + i]; }
    else             { s = i - E_EDGES; d = s; }
    int pos = rowptr[d] + atomicAdd(&cnt[d], 1);
    csr[pos] = s;
}

// ---------------- h = x@W + attention logits (8 nodes / block) ----------------
__global__ __launch_bounds__(128) void linear_alpha_k(
    const float* __restrict__ x, const float* __restrict__ W,
    const float* __restrict__ a_src, const float* __restrict__ a_dst,
    float* __restrict__ h, float* __restrict__ asrc, float* __restrict__ adst,
    int in_dim)
{
    __shared__ float xs[8][256];
    __shared__ float red[2][8][2];
    const int t = threadIdx.x;
    const int n0 = blockIdx.x * 8;
    for (int n = 0; n < 8; ++n)
        for (int i = t; i < in_dim; i += 128) xs[n][i] = x[(size_t)(n0 + n) * in_dim + i];
    __syncthreads();
    float acc[8] = {0.f,0.f,0.f,0.f,0.f,0.f,0.f,0.f};
    for (int i = 0; i < in_dim; ++i) {
        float wv = W[i * HID + t];
        #pragma unroll
        for (int n = 0; n < 8; ++n) acc[n] = fmaf(xs[n][i], wv, acc[n]);
    }
    #pragma unroll
    for (int n = 0; n < 8; ++n) h[(size_t)(n0 + n) * HID + t] = acc[n];
    const float As = a_src[t], Ad = a_dst[t];
    const int wv_ = t >> 6;
    #pragma unroll
    for (int n = 0; n < 8; ++n) {
        float vs = acc[n] * As, vd = acc[n] * Ad;
        #pragma unroll
        for (int off = 32; off; off >>= 1) {
            vs += __shfl_down(vs, off, 64);
            vd += __shfl_down(vd, off, 64);
        }
        if ((t & 63) == 0) { red[wv_][n][0] = vs; red[wv_][n][1] = vd; }
    }
    __syncthreads();
    if (t < 8) {
        asrc[n0 + t] = red[0][t][0] + red[1][t][0];
        adst[n0 + t] = red[0][t][1] + red[1][t][1];
    }
}

// -------- fused segment softmax + aggregate + bias + leakyrelu (block per dst) --------
// EMIT=0: write float out. EMIT=1: write bf16 hi/lo split (for the AA^T GEMM).
template<int EMIT>
__global__ __launch_bounds__(128) void gat_agg_k(
    const int* __restrict__ rowptr, const int* __restrict__ csr,
    const float* __restrict__ asrc, const float* __restrict__ adst,
    const float* __restrict__ h, const float* __restrict__ bias,
    float* __restrict__ out, unsigned short* __restrict__ hi,
    unsigned short* __restrict__ lo)
{
    __shared__ float w[256];
    __shared__ int   si[256];
    __shared__ float redm[2], reds[2];
    const int d = blockIdx.x;
    const int beg = rowptr[d];
    const int deg = rowptr[d + 1] - beg;
    const int t = threadIdx.x;
    const float ad = adst[d];

    float mx = -INFINITY;
    for (int j = t; j < deg; j += 128) {
        int s = csr[beg + j];
        float e = asrc[s] + ad; e = e >= 0.f ? e : NEG_ATT * e;
        if (j < 256) { w[j] = e; si[j] = s; }
        mx = fmaxf(mx, e);
    }
    #pragma unroll
    for (int off = 32; off; off >>= 1) mx = fmaxf(mx, __shfl_down(mx, off, 64));
    if ((t & 63) == 0) redm[t >> 6] = mx;
    __syncthreads();
    const float M = fmaxf(redm[0], redm[1]);

    float sm = 0.f;
    for (int j = t; j < deg; j += 128) {
        float e;
        if (j < 256) e = w[j];
        else { int s = csr[beg + j]; e = asrc[s] + ad; e = e >= 0.f ? e : NEG_ATT * e; }
        float ww = __expf(e - M);
        if (j < 256) w[j] = ww;
        sm += ww;
    }
    #pragma unroll
    for (int off = 32; off; off >>= 1) sm += __shfl_down(sm, off, 64);
    if ((t & 63) == 0) reds[t >> 6] = sm;
    __syncthreads();
    const float inv = 1.f / (reds[0] + reds[1]);

    float acc = 0.f;
    #pragma unroll 4
    for (int j = 0; j < deg; ++j) {
        int s; float ww;
        if (j < 256) { s = si[j]; ww = w[j]; }
        else {
            s = csr[beg + j];
            float e = asrc[s] + ad; e = e >= 0.f ? e : NEG_ATT * e;
            ww = __expf(e - M);
        }
        acc = fmaf(ww, h[(size_t)s * HID + t], acc);
    }
    float v = lrelu(fmaf(acc, inv, bias[t]), NEG_ACT);
    if (EMIT) {
        uint32_t u = __float_as_uint(v);
        uint32_t rh = (u + 0x7FFFu + ((u >> 16) & 1u)) & 0xFFFF0000u;
        float r = v - __uint_as_float(rh);
        uint32_t u2 = __float_as_uint(r);
        uint32_t rl = (u2 + 0x7FFFu + ((u2 >> 16) & 1u)) & 0xFFFF0000u;
        hi[(size_t)d * HID + t] = (unsigned short)(rh >> 16);
        lo[(size_t)d * HID + t] = (unsigned short)(rl >> 16);
    } else {
        out[(size_t)d * HID + t] = v;
    }
}

// ---------------- fp32 -> bf16 (hi, lo) split for layer-1 path (unused now) ----
// (cvt fused into gat_agg_k<1>)

// ---------------- C = A A^T via split-bf16 MFMA (hh + hl + lh) ----------------
// 128x128 tile / block (256 thr = 4 waves, each a 64x64 subtile of 4x4 16x16 frags).
// LDS: 4 panels [128 rows][64 k] bf16, 16B-chunk XOR swizzle (slot = c ^ (r&7)).
__global__ __launch_bounds__(256) void aat_mfma_k(
    const unsigned short* __restrict__ hi, const unsigned short* __restrict__ lo,
    float* __restrict__ C)
{
    __shared__ __align__(16) unsigned short sm[4][128 * 64];
    const int t = threadIdx.x;
    const int lane = t & 63, wv = t >> 6;
    const int bi = blockIdx.y * 128, bj = blockIdx.x * 128;
    const int wi0 = (wv >> 1) * 64, wj0 = (wv & 1) * 64;
    const int lr = lane & 15, g = lane >> 4;

    f32x4 acc[4][4] = {};

    const unsigned short* gsrc[4] = { hi, lo, hi, lo };
    const int gbase[4] = { bi, bi, bj, bj };

    for (int ks = 0; ks < 2; ++ks) {
        if (ks) __syncthreads();           // finish compute before re-staging
        #pragma unroll
        for (int arr = 0; arr < 4; ++arr) {
            const unsigned short* src = gsrc[arr];
            const int rb = gbase[arr];
            #pragma unroll
            for (int it = 0; it < 4; ++it) {
                int idx = it * 256 + t;
                int r = idx >> 3, c = idx & 7;
                float4 v = *(const float4*)(src + (size_t)(rb + r) * HID + ks * 64 + c * 8);
                ((float4*)sm[arr])[r * 8 + (c ^ (r & 7))] = v;
            }
        }
        __syncthreads();

        #pragma unroll
        for (int kw = 0; kw < 2; ++kw) {
            bf16x8 ah[4], al[4], bh[4], bl[4];
            #pragma unroll
            for (int f = 0; f < 4; ++f) {
                int rA = wi0 + f * 16 + lr;
                int csA = (kw * 4 + g) ^ (rA & 7);
                ah[f] = *(const bf16x8*)(sm[0] + rA * 64 + csA * 8);
                al[f] = *(const bf16x8*)(sm[1] + rA * 64 + csA * 8);
                int rB = wj0 + f * 16 + lr;
                int csB = (kw * 4 + g) ^ (rB & 7);
                bh[f] = *(const bf16x8*)(sm[2] + rB * 64 + csB * 8);
                bl[f] = *(const bf16x8*)(sm[3] + rB * 64 + csB * 8);
            }
            #pragma unroll
            for (int fi = 0; fi < 4; ++fi)
                #pragma unroll
                for (int fj = 0; fj < 4; ++fj) {
                    acc[fi][fj] = __builtin_amdgcn_mfma_f32_16x16x32_bf16(ah[fi], bh[fj], acc[fi][fj], 0, 0, 0);
                    acc[fi][fj] = __builtin_amdgcn_mfma_f32_16x16x32_bf16(ah[fi], bl[fj], acc[fi][fj], 0, 0, 0);
                    acc[fi][fj] = __builtin_amdgcn_mfma_f32_16x16x32_bf16(al[fi], bh[fj], acc[fi][fj], 0, 0, 0);
                }
        }
    }

    #pragma unroll
    for (int fi = 0; fi < 4; ++fi)
        #pragma unroll
        for (int q = 0; q < 4; ++q) {
            size_t row = (size_t)(bi + wi0 + fi * 16 + g * 4 + q);
            float* cp = C + row * N_NODES + bj + wj0 + lr;
            #pragma unroll
            for (int fj = 0; fj < 4; ++fj)
                __builtin_nontemporal_store(acc[fi][fj][q], cp + fj * 16);
        }
}

extern "C" void kernel_launch(void* const* d_in, const int* in_sizes, int n_in,
                              void* d_out, int out_size, void* d_ws, size_t ws_size,
                              hipStream_t stream)
{
    const float* x   = (const float*)d_in[0];
    const int*   ei  = (const int*)d_in[1];
    const float* W1  = (const float*)d_in[2];
    const float* a1s = (const float*)d_in[3];
    const float* a1d = (const float*)d_in[4];
    const float* b1  = (const float*)d_in[5];
    const float* W2  = (const float*)d_in[6];
    const float* a2s = (const float*)d_in[7];
    const float* a2d = (const float*)d_in[8];
    const float* b2  = (const float*)d_in[9];
    float* C = (float*)d_out;

    // workspace layout (16 MB total)
    char* base = (char*)d_ws;
    float* h   = (float*)base;                        // 4 MB
    float* act = (float*)(base + (4u << 20));         // 4 MB (act1)
    char*  aux = base + (8u << 20);                   // 4 MB graph data
    float* asrc   = (float*)aux;                      // 32 KB
    float* adst   = (float*)(aux + (32u << 10));      // 32 KB
    int*   rowptr = (int*)(aux + (64u << 10));        // 8193 ints
    int*   cnt    = (int*)(aux + (104u << 10));       // 32 KB
    int*   csr    = (int*)(aux + (136u << 10));       // ~1.06 MB
    unsigned short* hi = (unsigned short*)(base + (12u << 20)); // 2 MB
    unsigned short* lo = (unsigned short*)(base + (14u << 20)); // 2 MB

    const int eb = (ET + 255) / 256;

    // CSR build (shared by both layers), no memsets in-graph
    zero_k<<<8, 1024, 0, stream>>>(cnt);
    hist_k<<<eb, 256, 0, stream>>>(ei, cnt);
    scan_k<<<1, 1024, 0, stream>>>(cnt, rowptr);      // also re-zeroes cnt
    scatter_k<<<eb, 256, 0, stream>>>(ei, rowptr, cnt, csr);

    // layer 1
    linear_alpha_k<<<N_NODES / 8, 128, 0, stream>>>(x, W1, a1s, a1d, h, asrc, adst, IN_DIM);
    gat_agg_k<0><<<N_NODES, 128, 0, stream>>>(rowptr, csr, asrc, adst, h, b1, act, nullptr, nullptr);
    // layer 2 (emits bf16 hi/lo directly)
    linear_alpha_k<<<N_NODES / 8, 128, 0, stream>>>(act, W2, a2s, a2d, h, asrc, adst, HID);
    gat_agg_k<1><<<N_NODES, 128, 0, stream>>>(rowptr, csr, asrc, adst, h, b2, nullptr, hi, lo);

    // pred = act2 @ act2^T via split bf16 (hh + hl + lh; ll dropped, ~1e-4)
    aat_mfma_k<<<dim3(N_NODES / 128, N_NODES / 128), 256, 0, stream>>>(hi, lo, C);
}